// Round 1
// 302.040 us; speedup vs baseline: 1.0034x; 1.0034x over previous
//
#include <hip/hip_runtime.h>
#include <math.h>

// symLoss, two-stage:
//   stage1: grid = C*B blocks (C = ceil(N/256) chunks per batch), one point per
//           thread, S compile-time-unrolled => 2*S evals = ~4*2*S scattered
//           gathers in flight per thread. No LDS staging (points read once),
//           no atomics: per-block partial pair -> workspace.
//           b = bid % B => all chunks of a batch land on the same XCD (B%8==0),
//           sharing the 512KB vol+cp gather set in that XCD's L2.
//   stage2: 1 block, double-precision reduce of C*B partial pairs -> out.
// Removes: LDS stage+sync, 2*B serialized same-address atomics, 8B memset dispatch.

#define NGRID3     32768            // 32^3
#define GRID_MIN_F (-0.484375f)     // -0.5 + 0.5/32
#define NTHREADS   256

__device__ __forceinline__ float point_loss(float x, float y, float z,
                                            const float* __restrict__ vol,
                                            const float* __restrict__ cp)
{
    // jnp: clip to [0,31] then round (nearest-even) => rintf after clamp
    float fx = fminf(fmaxf((x - GRID_MIN_F) * 32.0f, 0.0f), 31.0f);
    float fy = fminf(fmaxf((y - GRID_MIN_F) * 32.0f, 0.0f), 31.0f);
    float fz = fminf(fmaxf((z - GRID_MIN_F) * 32.0f, 0.0f), 31.0f);
    int lin = ((int)rintf(fx)) * 1024 + ((int)rintf(fy)) * 32 + (int)rintf(fz);

    float m  = 1.0f - vol[lin];
    int  c3  = lin * 3;
    float dx = (x - cp[c3 + 0]) * m;
    float dy = (y - cp[c3 + 1]) * m;
    float dz = (z - cp[c3 + 2]) * m;
    return sqrtf(fmaxf(dx * dx + dy * dy + dz * dz, 1e-30f));
}

template <int S>
__global__ __launch_bounds__(NTHREADS, 4) void symloss_stage1(
    const float* __restrict__ planes,   // (S,B,4)
    const float* __restrict__ quats,    // (S,B,4)
    const float* __restrict__ cps,      // (B, 32768*3)
    const float* __restrict__ samples,  // (B,N,3)
    const float* __restrict__ volume,   // (B, 32768)
    float* __restrict__ partials,       // (grid, 2)
    int B, int N)
{
    const int bid = blockIdx.x;
    const int b   = bid % B;            // chunk-major: same batch -> same XCD
    const int c   = bid / B;

    const float* __restrict__ vol = volume + (size_t)b * NGRID3;
    const float* __restrict__ cp  = cps    + (size_t)b * NGRID3 * 3;

    // per-s transform params (uniform across block -> scalarized loads)
    float plx[S], ply[S], plz[S], plw[S], inv_n2[S];
    float qw[S], qx[S], qy[S], qz[S], w2mu[S];
#pragma unroll
    for (int s = 0; s < S; ++s) {
        float4 pl = ((const float4*)planes)[(size_t)s * B + b];
        float4 q  = ((const float4*)quats )[(size_t)s * B + b];
        plx[s] = pl.x; ply[s] = pl.y; plz[s] = pl.z; plw[s] = pl.w;
        inv_n2[s] = 1.0f / (pl.x * pl.x + pl.y * pl.y + pl.z * pl.z + 1e-8f);
        qw[s] = q.x; qx[s] = q.y; qy[s] = q.z; qz[s] = q.w;
        w2mu[s] = q.x * q.x - (q.y * q.y + q.z * q.z + q.w * q.w);
    }

    float sum_p = 0.0f, sum_q = 0.0f;
    const int n = c * NTHREADS + (int)threadIdx.x;
    if (n < N) {
        const float* sp = samples + ((size_t)b * N + n) * 3;
        const float px = sp[0];
        const float py = sp[1];
        const float pz = sp[2];
#pragma unroll
        for (int s = 0; s < S; ++s) {
            // plane reflection
            float f = 2.0f * (px * plx[s] + py * ply[s] + pz * plz[s] + plw[s]) * inv_n2[s];
            sum_p += point_loss(px - f * plx[s], py - f * ply[s], pz - f * plz[s], vol, cp);

            // quaternion rotate (unnormalized): (w^2-|u|^2)p + 2(u.p)u + 2w(u x p)
            float udp = qx[s] * px + qy[s] * py + qz[s] * pz;
            float cx  = qy[s] * pz - qz[s] * py;
            float cy  = qz[s] * px - qx[s] * pz;
            float cz  = qx[s] * py - qy[s] * px;
            sum_q += point_loss(w2mu[s] * px + 2.0f * (udp * qx[s] + qw[s] * cx),
                                w2mu[s] * py + 2.0f * (udp * qy[s] + qw[s] * cy),
                                w2mu[s] * pz + 2.0f * (udp * qz[s] + qw[s] * cz),
                                vol, cp);
        }
    }

    // wave shuffle reduce (64-wide) then LDS across 4 waves
    for (int off = 32; off > 0; off >>= 1) {
        sum_p += __shfl_down(sum_p, off);
        sum_q += __shfl_down(sum_q, off);
    }
    __shared__ float red[NTHREADS / 64][2];
    const int lane = threadIdx.x & 63;
    const int wid  = threadIdx.x >> 6;
    if (lane == 0) { red[wid][0] = sum_p; red[wid][1] = sum_q; }
    __syncthreads();

    if (threadIdx.x == 0) {
        float tp = 0.0f, tq = 0.0f;
        for (int w = 0; w < NTHREADS / 64; ++w) { tp += red[w][0]; tq += red[w][1]; }
        partials[2 * bid + 0] = tp;
        partials[2 * bid + 1] = tq;
    }
}

__global__ __launch_bounds__(NTHREADS) void symloss_reduce(
    const float* __restrict__ partials, int M, float scale,
    float* __restrict__ out)
{
    double sp = 0.0, sq = 0.0;
    for (int i = threadIdx.x; i < M; i += NTHREADS) {
        sp += (double)partials[2 * i + 0];
        sq += (double)partials[2 * i + 1];
    }
    for (int off = 32; off > 0; off >>= 1) {
        sp += __shfl_down(sp, off);
        sq += __shfl_down(sq, off);
    }
    __shared__ double red[NTHREADS / 64][2];
    const int lane = threadIdx.x & 63;
    const int wid  = threadIdx.x >> 6;
    if (lane == 0) { red[wid][0] = sp; red[wid][1] = sq; }
    __syncthreads();
    if (threadIdx.x == 0) {
        double tp = 0.0, tq = 0.0;
        for (int w = 0; w < NTHREADS / 64; ++w) { tp += red[w][0]; tq += red[w][1]; }
        out[0] = (float)(tp * (double)scale);
        out[1] = (float)(tq * (double)scale);
    }
}

extern "C" void kernel_launch(void* const* d_in, const int* in_sizes, int n_in,
                              void* d_out, int out_size, void* d_ws, size_t ws_size,
                              hipStream_t stream)
{
    const float* planes  = (const float*)d_in[0];
    const float* quats   = (const float*)d_in[1];
    const float* cps     = (const float*)d_in[2];
    const float* samples = (const float*)d_in[3];
    const float* volume  = (const float*)d_in[4];
    float* out = (float*)d_out;

    const int B = in_sizes[4] / NGRID3;     // 512
    const int S = in_sizes[0] / (B * 4);    // 3
    const int N = in_sizes[3] / (B * 3);    // 1000
    const int C = (N + NTHREADS - 1) / NTHREADS;  // chunks per batch (4)
    const float scale = 1.0f / (float)(S * B);

    float* partials = (float*)d_ws;
    int M = C * B;

    switch (S) {
    case 1: symloss_stage1<1><<<C * B, NTHREADS, 0, stream>>>(planes, quats, cps, samples, volume, partials, B, N); break;
    case 2: symloss_stage1<2><<<C * B, NTHREADS, 0, stream>>>(planes, quats, cps, samples, volume, partials, B, N); break;
    case 3: symloss_stage1<3><<<C * B, NTHREADS, 0, stream>>>(planes, quats, cps, samples, volume, partials, B, N); break;
    case 4: symloss_stage1<4><<<C * B, NTHREADS, 0, stream>>>(planes, quats, cps, samples, volume, partials, B, N); break;
    default:
        for (int s = 0; s < S; ++s)
            symloss_stage1<1><<<C * B, NTHREADS, 0, stream>>>(
                planes + (size_t)s * B * 4, quats + (size_t)s * B * 4,
                cps, samples, volume, partials + (size_t)s * C * B * 2, B, N);
        M = S * C * B;
        break;
    }

    symloss_reduce<<<1, NTHREADS, 0, stream>>>(partials, M, scale, out);
}

// Round 2
// 300.884 us; speedup vs baseline: 1.0073x; 1.0038x over previous
//
#include <hip/hip_runtime.h>
#include <math.h>

// symLoss, two-stage, XCD-batch-window edition:
//   stage1: each batch gets C=8 blocks x 512 threads = 4096 threads covering
//           N*2*S = 6000 eval items (type-major: all plane evals, then all
//           quat evals => waves are type-uniform, no divergent gather dup).
//           Block mapping  x=bid%8, g=bid/8, c=g%C, b=(g/C)*8+x  keeps all C
//           blocks of a batch co-resident on ONE XCD, and limits each XCD to
//           a sliding window of 64/C = 8 concurrent batches => 8 x 512KB =
//           4MB = L2. First touch of each vol/cp line is compulsory HBM
//           (L3 is evicted by the harness' 768MB workspace poison each iter);
//           all reuse (~53% of touches) is then served by L2 instead of L3.
//   stage2: 1 block, double-precision reduce of B*C partial pairs -> out.

#define NGRID3     32768            // 32^3
#define GRID_MIN_F (-0.484375f)     // -0.5 + 0.5/32
#define T1         512              // stage1 block size (8 waves)
#define T2         256

__device__ __forceinline__ float point_loss(float x, float y, float z,
                                            const float* __restrict__ vol,
                                            const float* __restrict__ cp)
{
    // jnp: clip to [0,31] then round (nearest-even) => rintf after clamp
    float fx = fminf(fmaxf((x - GRID_MIN_F) * 32.0f, 0.0f), 31.0f);
    float fy = fminf(fmaxf((y - GRID_MIN_F) * 32.0f, 0.0f), 31.0f);
    float fz = fminf(fmaxf((z - GRID_MIN_F) * 32.0f, 0.0f), 31.0f);
    int lin = ((int)rintf(fx)) * 1024 + ((int)rintf(fy)) * 32 + (int)rintf(fz);

    float m  = 1.0f - vol[lin];
    int  c3  = lin * 3;
    float dx = (x - cp[c3 + 0]) * m;
    float dy = (y - cp[c3 + 1]) * m;
    float dz = (z - cp[c3 + 2]) * m;
    return sqrtf(fmaxf(dx * dx + dy * dy + dz * dz, 1e-30f));
}

template <int S>
__global__ __launch_bounds__(T1, 4) void symloss_stage1(
    const float* __restrict__ planes,   // (S,B,4)
    const float* __restrict__ quats,    // (S,B,4)
    const float* __restrict__ cps,      // (B, 32768*3)
    const float* __restrict__ samples,  // (B,N,3)
    const float* __restrict__ volume,   // (B, 32768)
    float* __restrict__ partials,       // (grid, 2)
    int B, int N, int C, int xcd_map)
{
    const int bid = blockIdx.x;
    int b, c;
    if (xcd_map) {
        // same-XCD sliding window: all C blocks of a batch on one XCD,
        // <= 64/C batches concurrently active per XCD.
        const int x = bid & 7;
        const int g = bid >> 3;
        c = g % C;
        b = (g / C) * 8 + x;
    } else {
        b = bid / C;
        c = bid % C;
    }

    const float* __restrict__ vol = volume + (size_t)b * NGRID3;
    const float* __restrict__ cp  = cps    + (size_t)b * NGRID3 * 3;
    const float* __restrict__ sp  = samples + (size_t)b * N * 3;

    const int items  = N * 2 * S;       // type-major: [0,N*S) plane, [N*S,2*N*S) quat
    const int stride = C * T1;
    const int tib    = c * T1 + (int)threadIdx.x;

    float sum_p = 0.0f, sum_q = 0.0f;

    for (int e = tib; e < items; e += stride) {
        const bool is_q = (e >= N * S);
        const int idx   = is_q ? (e - N * S) : e;
        const int n     = idx / S;          // S compile-time => magic-mul
        const int s     = idx - n * S;

        const float px = sp[n * 3 + 0];
        const float py = sp[n * 3 + 1];
        const float pz = sp[n * 3 + 2];

        if (!is_q) {
            const float4 pl = ((const float4*)planes)[(size_t)s * B + b];
            const float inv_n2 = 1.0f / (pl.x * pl.x + pl.y * pl.y + pl.z * pl.z + 1e-8f);
            const float f = 2.0f * (px * pl.x + py * pl.y + pz * pl.z + pl.w) * inv_n2;
            sum_p += point_loss(px - f * pl.x, py - f * pl.y, pz - f * pl.z, vol, cp);
        } else {
            const float4 q = ((const float4*)quats)[(size_t)s * B + b];
            const float qw = q.x, qx = q.y, qy = q.z, qz = q.w;
            const float w2mu = qw * qw - (qx * qx + qy * qy + qz * qz);
            const float udp = qx * px + qy * py + qz * pz;
            const float cx  = qy * pz - qz * py;
            const float cy  = qz * px - qx * pz;
            const float cz  = qx * py - qy * px;
            sum_q += point_loss(w2mu * px + 2.0f * (udp * qx + qw * cx),
                                w2mu * py + 2.0f * (udp * qy + qw * cy),
                                w2mu * pz + 2.0f * (udp * qz + qw * cz),
                                vol, cp);
        }
    }

    // wave shuffle reduce (64-wide) then LDS across 8 waves
    for (int off = 32; off > 0; off >>= 1) {
        sum_p += __shfl_down(sum_p, off);
        sum_q += __shfl_down(sum_q, off);
    }
    __shared__ float red[T1 / 64][2];
    const int lane = threadIdx.x & 63;
    const int wid  = threadIdx.x >> 6;
    if (lane == 0) { red[wid][0] = sum_p; red[wid][1] = sum_q; }
    __syncthreads();

    if (threadIdx.x == 0) {
        float tp = 0.0f, tq = 0.0f;
        for (int w = 0; w < T1 / 64; ++w) { tp += red[w][0]; tq += red[w][1]; }
        partials[2 * bid + 0] = tp;
        partials[2 * bid + 1] = tq;
    }
}

__global__ __launch_bounds__(T2) void symloss_reduce(
    const float* __restrict__ partials, int M, float scale,
    float* __restrict__ out)
{
    double sp = 0.0, sq = 0.0;
    for (int i = threadIdx.x; i < M; i += T2) {
        sp += (double)partials[2 * i + 0];
        sq += (double)partials[2 * i + 1];
    }
    for (int off = 32; off > 0; off >>= 1) {
        sp += __shfl_down(sp, off);
        sq += __shfl_down(sq, off);
    }
    __shared__ double red[T2 / 64][2];
    const int lane = threadIdx.x & 63;
    const int wid  = threadIdx.x >> 6;
    if (lane == 0) { red[wid][0] = sp; red[wid][1] = sq; }
    __syncthreads();
    if (threadIdx.x == 0) {
        double tp = 0.0, tq = 0.0;
        for (int w = 0; w < T2 / 64; ++w) { tp += red[w][0]; tq += red[w][1]; }
        out[0] = (float)(tp * (double)scale);
        out[1] = (float)(tq * (double)scale);
    }
}

extern "C" void kernel_launch(void* const* d_in, const int* in_sizes, int n_in,
                              void* d_out, int out_size, void* d_ws, size_t ws_size,
                              hipStream_t stream)
{
    const float* planes  = (const float*)d_in[0];
    const float* quats   = (const float*)d_in[1];
    const float* cps     = (const float*)d_in[2];
    const float* samples = (const float*)d_in[3];
    const float* volume  = (const float*)d_in[4];
    float* out = (float*)d_out;

    const int B = in_sizes[4] / NGRID3;     // 512
    const int S = in_sizes[0] / (B * 4);    // 3
    const int N = in_sizes[3] / (B * 3);    // 1000
    const float scale = 1.0f / (float)(S * B);

    // C blocks per batch: at least enough for <=2 eval items per thread, and
    // >=8 so the per-XCD batch window (64/C) fits L2 (8 x 512KB = 4MB).
    const int items = N * 2 * S;
    int C = (items + 2 * T1 - 1) / (2 * T1);
    if (C < 8) C = 8;
    const int xcd_map = (B % 8 == 0) ? 1 : 0;

    float* partials = (float*)d_ws;
    int M = B * C;

    switch (S) {
    case 1: symloss_stage1<1><<<B * C, T1, 0, stream>>>(planes, quats, cps, samples, volume, partials, B, N, C, xcd_map); break;
    case 2: symloss_stage1<2><<<B * C, T1, 0, stream>>>(planes, quats, cps, samples, volume, partials, B, N, C, xcd_map); break;
    case 3: symloss_stage1<3><<<B * C, T1, 0, stream>>>(planes, quats, cps, samples, volume, partials, B, N, C, xcd_map); break;
    case 4: symloss_stage1<4><<<B * C, T1, 0, stream>>>(planes, quats, cps, samples, volume, partials, B, N, C, xcd_map); break;
    default:
        for (int s = 0; s < S; ++s)
            symloss_stage1<1><<<B * C, T1, 0, stream>>>(
                planes + (size_t)s * B * 4, quats + (size_t)s * B * 4,
                cps, samples, volume, partials + (size_t)s * B * C * 2,
                B, N, C, xcd_map);
        M = S * B * C;
        break;
    }

    symloss_reduce<<<1, T2, 0, stream>>>(partials, M, scale, out);
}